// Round 1
// baseline (1104.787 us; speedup 1.0000x reference)
//
#include <hip/hip_runtime.h>

#define HH 64
#define WW 64
#define CC 128
#define HWSZ 4096   // 64*64

// ---------------------------------------------------------------------------
// Direct 3x3 conv, pad 1, stride 1.  Tile: 16x16 pixels x OC_TILE channels.
// Input channels staged in LDS in chunks of ICC.  Weights read via
// block-uniform indices -> scalar loads (SGPR operands to the FMAs).
// Optional: BN_IN applies y = relu(scale*x+shift) to the *input* while
// loading the tile; STATS accumulates per-channel sum/sumsq of the output;
// ATOMIC accumulates output with atomicAdd (used by the ic-split offset conv).
// ---------------------------------------------------------------------------
template<int OC_TILE, int ICC, bool BN_IN, bool STATS, bool ATOMIC>
__global__ __launch_bounds__(256)
void conv3x3_k(const float* __restrict__ in, const float* __restrict__ wgt,
               const float* __restrict__ bias,
               const float* __restrict__ bnscale, const float* __restrict__ bnshift,
               float* __restrict__ out, float* __restrict__ ssum, float* __restrict__ ssq,
               int oc_total, int oc_groups, int n_split)
{
    __shared__ float tile[ICC][18][18];
    const int tid = threadIdx.x;
    const int tx = tid & 15, ty = tid >> 4;
    const int bx = blockIdx.x * 16, by = blockIdx.y * 16;
    int z = blockIdx.z;
    const int split = z % n_split; z /= n_split;
    const int ocg = z % oc_groups;
    const int b = z / oc_groups;
    const int oc0 = ocg * OC_TILE;
    const int icps = CC / n_split;
    const int ic_start = split * icps;

    float acc[OC_TILE];
#pragma unroll
    for (int o = 0; o < OC_TILE; ++o)
        acc[o] = (ATOMIC && ic_start != 0) ? 0.f : bias[oc0 + o];

    const float* inb = in + (size_t)b * CC * HWSZ;

    for (int ic0 = ic_start; ic0 < ic_start + icps; ic0 += ICC) {
        __syncthreads();
        for (int i = tid; i < ICC * 324; i += 256) {
            int ic = i / 324;
            int rem = i - ic * 324;
            int r = rem / 18;
            int cl = rem - r * 18;
            int gy = by + r - 1, gx = bx + cl - 1;
            float v = 0.f;
            if ((unsigned)gy < (unsigned)HH && (unsigned)gx < (unsigned)WW) {
                v = inb[(ic0 + ic) * HWSZ + gy * WW + gx];
                if (BN_IN)
                    v = fmaxf(fmaf(v, bnscale[ic0 + ic], bnshift[ic0 + ic]), 0.f);
            }
            tile[ic][r][cl] = v;
        }
        __syncthreads();
#pragma unroll
        for (int ic = 0; ic < ICC; ++ic) {
            float t00 = tile[ic][ty + 0][tx + 0], t01 = tile[ic][ty + 0][tx + 1], t02 = tile[ic][ty + 0][tx + 2];
            float t10 = tile[ic][ty + 1][tx + 0], t11 = tile[ic][ty + 1][tx + 1], t12 = tile[ic][ty + 1][tx + 2];
            float t20 = tile[ic][ty + 2][tx + 0], t21 = tile[ic][ty + 2][tx + 1], t22 = tile[ic][ty + 2][tx + 2];
            // block-uniform weight pointer -> scalar loads
            const float* wp = wgt + ((size_t)oc0 * CC + (ic0 + ic)) * 9;
#pragma unroll
            for (int o = 0; o < OC_TILE; ++o) {
                const float* w9 = wp + o * CC * 9;
                acc[o] = fmaf(t00, w9[0], acc[o]);
                acc[o] = fmaf(t01, w9[1], acc[o]);
                acc[o] = fmaf(t02, w9[2], acc[o]);
                acc[o] = fmaf(t10, w9[3], acc[o]);
                acc[o] = fmaf(t11, w9[4], acc[o]);
                acc[o] = fmaf(t12, w9[5], acc[o]);
                acc[o] = fmaf(t20, w9[6], acc[o]);
                acc[o] = fmaf(t21, w9[7], acc[o]);
                acc[o] = fmaf(t22, w9[8], acc[o]);
            }
        }
    }

    const int oy = by + ty, ox = bx + tx;
    float* ob = out + (size_t)b * oc_total * HWSZ + oy * WW + ox;
#pragma unroll
    for (int o = 0; o < OC_TILE; ++o) {
        if (ATOMIC) atomicAdd(&ob[(oc0 + o) * HWSZ], acc[o]);
        else        ob[(oc0 + o) * HWSZ] = acc[o];
    }

    if (STATS) {
#pragma unroll
        for (int o = 0; o < OC_TILE; ++o) {
            float s = acc[o], q = acc[o] * acc[o];
            for (int d = 32; d > 0; d >>= 1) {
                s += __shfl_down(s, d);
                q += __shfl_down(q, d);
            }
            if ((tid & 63) == 0) {
                atomicAdd(&ssum[oc0 + o], s);
                atomicAdd(&ssq[oc0 + o], q);
            }
        }
    }
}

// ---------------------------------------------------------------------------
// Deformable 3x3 conv (deform_groups=1, pad 1, stride 1, zero-pad sampling).
// Per thread: one pixel, 16 output channels.  Precompute the 9 taps' four
// clamped corner indices + validity-folded bilinear weights, then loop input
// channels: one 4-gather blend per (ic,tap), reused across the 16 oc FMAs
// (weights arrive as scalar loads).
// ---------------------------------------------------------------------------
__global__ __launch_bounds__(256)
void dconv_k(const float* __restrict__ x, const float* __restrict__ off,
             const float* __restrict__ wd, const float* __restrict__ bd,
             float* __restrict__ dout)
{
    const int tid = threadIdx.x;
    const int tx = tid & 15, ty = tid >> 4;
    const int px = blockIdx.x * 16 + tx;
    const int py = blockIdx.y * 16 + ty;
    const int b = blockIdx.z >> 3;
    const int oc0 = (blockIdx.z & 7) * 16;

    int   idx4[9][4];
    float wt4[9][4];
    const float* offb = off + (size_t)b * 18 * HWSZ + py * WW + px;
#pragma unroll
    for (int k = 0; k < 9; ++k) {
        const int ky = k / 3 - 1, kx = k % 3 - 1;
        float dy = offb[(2 * k + 0) * HWSZ];
        float dx = offb[(2 * k + 1) * HWSZ];
        float fy = (float)(py + ky) + dy;
        float fx = (float)(px + kx) + dx;
        float yl = floorf(fy), xl = floorf(fx);
        float ly = fy - yl, lx = fx - xl;
        int iy0 = (int)yl, ix0 = (int)xl;
        int iy1 = iy0 + 1, ix1 = ix0 + 1;
        float vy0 = (iy0 >= 0 && iy0 < HH) ? 1.f : 0.f;
        float vy1 = (iy1 >= 0 && iy1 < HH) ? 1.f : 0.f;
        float vx0 = (ix0 >= 0 && ix0 < WW) ? 1.f : 0.f;
        float vx1 = (ix1 >= 0 && ix1 < WW) ? 1.f : 0.f;
        int iy0c = min(max(iy0, 0), HH - 1), iy1c = min(max(iy1, 0), HH - 1);
        int ix0c = min(max(ix0, 0), WW - 1), ix1c = min(max(ix1, 0), WW - 1);
        wt4[k][0] = (1.f - ly) * (1.f - lx) * vy0 * vx0;
        wt4[k][1] = (1.f - ly) * lx         * vy0 * vx1;
        wt4[k][2] = ly         * (1.f - lx) * vy1 * vx0;
        wt4[k][3] = ly         * lx         * vy1 * vx1;
        idx4[k][0] = iy0c * WW + ix0c;
        idx4[k][1] = iy0c * WW + ix1c;
        idx4[k][2] = iy1c * WW + ix0c;
        idx4[k][3] = iy1c * WW + ix1c;
    }

    float acc[16];
#pragma unroll
    for (int o = 0; o < 16; ++o) acc[o] = bd[oc0 + o];

    const float* xb = x + (size_t)b * CC * HWSZ;
    for (int ic = 0; ic < CC; ++ic) {
        const float* xc = xb + ic * HWSZ;
        const float* wp = wd + ((size_t)oc0 * CC + ic) * 9;   // uniform -> s_load
#pragma unroll
        for (int k = 0; k < 9; ++k) {
            float s =      wt4[k][0] * xc[idx4[k][0]];
            s = fmaf(wt4[k][1], xc[idx4[k][1]], s);
            s = fmaf(wt4[k][2], xc[idx4[k][2]], s);
            s = fmaf(wt4[k][3], xc[idx4[k][3]], s);
#pragma unroll
            for (int o = 0; o < 16; ++o)
                acc[o] = fmaf(s, wp[o * CC * 9 + k], acc[o]);
        }
    }

    float* ob = dout + ((size_t)b * CC + oc0) * HWSZ + py * WW + px;
#pragma unroll
    for (int o = 0; o < 16; ++o)
        ob[o * HWSZ] = acc[o];
}

// mean/var -> (scale, shift) per channel
__global__ void bnstat_k(const float* __restrict__ ssum, const float* __restrict__ ssq,
                         const float* __restrict__ g, const float* __restrict__ bet,
                         float* __restrict__ scale, float* __restrict__ shift)
{
    int c = threadIdx.x;
    const float invn = 1.f / (4.f * HWSZ);
    float mean = ssum[c] * invn;
    float var  = ssq[c] * invn - mean * mean;
    float sc = g[c] * rsqrtf(var + 1e-5f);
    scale[c] = sc;
    shift[c] = fmaf(-mean, sc, bet[c]);
}

// out = relu(dout + bn2(y2)), vectorized float4
__global__ __launch_bounds__(256)
void final_k(const float* __restrict__ dout, const float* __restrict__ y2,
             const float* __restrict__ scale, const float* __restrict__ shift,
             float* __restrict__ out)
{
    int i = blockIdx.x * 256 + threadIdx.x;       // over 2M/4 float4s
    int c = (i >> 10) & 127;                      // channel of this float4
    float4 d = reinterpret_cast<const float4*>(dout)[i];
    float4 y = reinterpret_cast<const float4*>(y2)[i];
    float sc = scale[c], sh = shift[c];
    float4 r;
    r.x = fmaxf(d.x + fmaf(y.x, sc, sh), 0.f);
    r.y = fmaxf(d.y + fmaf(y.y, sc, sh), 0.f);
    r.z = fmaxf(d.z + fmaf(y.z, sc, sh), 0.f);
    r.w = fmaxf(d.w + fmaf(y.w, sc, sh), 0.f);
    reinterpret_cast<float4*>(out)[i] = r;
}

extern "C" void kernel_launch(void* const* d_in, const int* in_sizes, int n_in,
                              void* d_out, int out_size, void* d_ws, size_t ws_size,
                              hipStream_t stream)
{
    const float* x     = (const float*)d_in[0];
    const float* w_off = (const float*)d_in[1];
    const float* b_off = (const float*)d_in[2];
    const float* w_d   = (const float*)d_in[3];
    const float* b_d   = (const float*)d_in[4];
    const float* w1    = (const float*)d_in[5];
    const float* b1    = (const float*)d_in[6];
    const float* g1    = (const float*)d_in[7];
    const float* be1   = (const float*)d_in[8];
    const float* w2    = (const float*)d_in[9];
    const float* b2    = (const float*)d_in[10];
    const float* g2    = (const float*)d_in[11];
    const float* be2   = (const float*)d_in[12];

    float* ws      = (float*)d_ws;
    float* off_buf = ws;                      // B*18*H*W       = 294912
    float* y1      = off_buf + 294912;        // B*C*H*W        = 2097152
    float* y2      = y1 + 2097152;
    float* dob     = y2 + 2097152;
    float* st      = dob + 2097152;           // 1024 floats of stats/params
    // st layout: sum1[128] sq1[128] sum2[128] sq2[128] scale1[128] shift1[128] scale2[128] shift2[128]

    hipMemsetAsync(off_buf, 0, 294912 * sizeof(float), stream);
    hipMemsetAsync(st, 0, 512 * sizeof(float), stream);

    // offset conv (18 ch), split 4-ways over input channels, atomic accumulate
    conv3x3_k<18, 8, false, false, true><<<dim3(4, 4, 4 * 4), 256, 0, stream>>>(
        x, w_off, b_off, nullptr, nullptr, off_buf, nullptr, nullptr, 18, 1, 4);

    // deformable conv -> dob
    dconv_k<<<dim3(4, 4, 32), 256, 0, stream>>>(x, off_buf, w_d, b_d, dob);

    // conv1 (+ BN1 stats) -> y1
    conv3x3_k<16, 8, false, true, false><<<dim3(4, 4, 32), 256, 0, stream>>>(
        x, w1, b1, nullptr, nullptr, y1, st, st + 128, 128, 8, 1);
    bnstat_k<<<1, 128, 0, stream>>>(st, st + 128, g1, be1, st + 512, st + 640);

    // conv2 on relu(bn1(y1)) applied during tile load (+ BN2 stats) -> y2
    conv3x3_k<16, 8, true, true, false><<<dim3(4, 4, 32), 256, 0, stream>>>(
        y1, w2, b2, st + 512, st + 640, y2, st + 256, st + 384, 128, 8, 1);
    bnstat_k<<<1, 128, 0, stream>>>(st + 256, st + 384, g2, be2, st + 768, st + 896);

    // out = relu(dob + bn2(y2))
    final_k<<<dim3(2048), 256, 0, stream>>>(dob, y2, st + 768, st + 896, (float*)d_out);
}